// Round 8
// baseline (121.570 us; speedup 1.0000x reference)
//
#include <hip/hip_runtime.h>

#define NI 8
#define NF 100
#define NH 40
#define NC 40
#define NM 41
#define BSZ 2048
#define BT 64
#define XPAD 104   // x-tile LDS row stride (floats), zero-padded 100..103

typedef __attribute__((ext_vector_type(8))) short bf16x8;
typedef __attribute__((ext_vector_type(4))) float f32x4;
typedef __attribute__((ext_vector_type(4))) unsigned int u32x4;

__device__ __forceinline__ unsigned short f2bf(float f) {
    unsigned int u = __builtin_bit_cast(unsigned int, f);
    u += 0x7fffu + ((u >> 16) & 1u);
    return (unsigned short)(u >> 16);
}
__device__ __forceinline__ bf16x8 pack8(float4 u, float4 v) {
    u32x4 w;
    w.x = (unsigned int)f2bf(u.x) | ((unsigned int)f2bf(u.y) << 16);
    w.y = (unsigned int)f2bf(u.z) | ((unsigned int)f2bf(u.w) << 16);
    w.z = (unsigned int)f2bf(v.x) | ((unsigned int)f2bf(v.y) << 16);
    w.w = (unsigned int)f2bf(v.z) | ((unsigned int)f2bf(v.w) << 16);
    return __builtin_bit_cast(bf16x8, w);
}
// async global->LDS DMA: 64 lanes x 16B; LDS dest = wave-uniform base, HW adds lane*16
__device__ __forceinline__ void gl2lds16(const void* g, void* l) {
    __builtin_amdgcn_global_load_lds(
        (const __attribute__((address_space(1))) unsigned int*)g,
        (__attribute__((address_space(3))) unsigned int*)l, 16, 0, 0);
}

// ---------------------------------------------------------------------------
// K1: W_ic = A_ic @ B_ic (fp32), emit bf16 MFMA B-frags (layouts verified R2-R7).
//   Wb1: [ic][nt(3)][k(4)][lane(64)] x16B; n=nt*16+(lane&15), f=k*32+(lane>>4)*8+j
//   Wb2: [ic][nt(7)][kk(2)][lane(64)] x16B; n=nt*16+(lane&15), h=kk*32+(lane>>4)*8+j
// ---------------------------------------------------------------------------
__global__ __launch_bounds__(512) void build_w_kernel(
    const float* __restrict__ A, const float* __restrict__ Bp,
    unsigned short* __restrict__ Wb1, unsigned short* __restrict__ Wb2)
{
    __shared__ __align__(16) float As[NF * NM];
    __shared__ __align__(16) float Bs[NM * NH];
    __shared__ __align__(16) float Ws[NF * NH];
    const int ic = blockIdx.x;
    const float* Ap  = A  + (size_t)ic * NF * NM;
    const float* Bpp = Bp + (size_t)ic * NM * NH;
    for (int idx = threadIdx.x; idx < NF * NM; idx += 512) As[idx] = Ap[idx];
    for (int idx = threadIdx.x; idx < NM * NH; idx += 512) Bs[idx] = Bpp[idx];
    __syncthreads();
    for (int idx = threadIdx.x; idx < NF * (NH / 4); idx += 512) {
        const int f  = idx / (NH / 4);
        const int hq = idx % (NH / 4);
        float4 acc = make_float4(0.f, 0.f, 0.f, 0.f);
        #pragma unroll
        for (int m = 0; m < NM; ++m) {
            const float  a = As[f * NM + m];
            const float4 b = *(const float4*)&Bs[m * NH + hq * 4];
            acc.x += a * b.x; acc.y += a * b.y; acc.z += a * b.z; acc.w += a * b.w;
        }
        *(float4*)&Ws[f * NH + hq * 4] = acc;
    }
    __syncthreads();

    for (int e = threadIdx.x; e < 768; e += 512) {
        const int nt = e >> 8, k = (e >> 6) & 3, ln = e & 63;
        const int colx = ln & 15, quad = ln >> 4;
        const int h = nt * 16 + colx;
        unsigned int w[4];
        #pragma unroll
        for (int jj = 0; jj < 4; ++jj) {
            const int f0 = k * 32 + quad * 8 + jj * 2;
            const int f1 = f0 + 1;
            const unsigned int lo = (f0 < NF && h < NH) ? f2bf(Ws[f0 * NH + h]) : 0;
            const unsigned int hi = (f1 < NF && h < NH) ? f2bf(Ws[f1 * NH + h]) : 0;
            w[jj] = lo | (hi << 16);
        }
        ((u32x4*)Wb1)[(size_t)ic * 768 + e] = (u32x4){w[0], w[1], w[2], w[3]};
    }
    for (int e = threadIdx.x; e < 896; e += 512) {
        const int nt = e >> 7, kk = (e >> 6) & 1, ln = e & 63;
        const int colx = ln & 15, quad = ln >> 4;
        const int f = nt * 16 + colx;
        unsigned int w[4];
        #pragma unroll
        for (int jj = 0; jj < 4; ++jj) {
            const int h0 = kk * 32 + quad * 8 + jj * 2;
            const int h1 = h0 + 1;
            const unsigned int lo = (f < NF && h0 < NH) ? f2bf(Ws[f * NH + h0]) : 0;
            const unsigned int hi = (f < NF && h1 < NH) ? f2bf(Ws[f * NH + h1]) : 0;
            w[jj] = lo | (hi << 16);
        }
        ((u32x4*)Wb2)[(size_t)ic * 896 + e] = (u32x4){w[0], w[1], w[2], w[3]};
    }
}

// ---------------------------------------------------------------------------
// P1: pass1, c-split. grid 512 = 32 bt x 8 i x 2 ch; 256 threads (4 waves).
// Block streams its 20 c's of Wb1 (240 KB); wave w owns mt=w (3 tiles, balanced).
// Writes fp32 h-partials to hpart[ch][bt][i][64][40].
// 512 blocks -> 2 blocks/CU co-resident: barrier drains overlap across blocks.
// ---------------------------------------------------------------------------
__global__ __launch_bounds__(256, 2) void pass1_kernel(
    const float* __restrict__ x, const float* __restrict__ mask,
    const unsigned short* __restrict__ Wb1, float* __restrict__ hpart)
{
    __shared__ __align__(16) unsigned char wbuf[2 * 24576];  // 2 x (2c x 12KB)
    __shared__ __align__(16) float xs[BT * XPAD];            // 26624 B
    __shared__ unsigned char msx[BT * 20];                   // 1280 B

    const int tid  = threadIdx.x;
    const int lane = tid & 63;
    const int wav  = tid >> 6;       // 0..3 == owned mt
    const int col  = lane & 15;
    const int quad = lane >> 4;
    const int i    = blockIdx.x & 7;
    const int ch   = (blockIdx.x >> 3) & 1;
    const int bt   = blockIdx.x >> 4;          // 0..31
    const int b0   = bt * BT;
    const int c0   = ch * 20;

    const unsigned char* wb1B = (const unsigned char*)Wb1
        + ((size_t)i * NC + c0) * 12288;       // 20 contiguous c-slabs

    // ---- prefetch super-iter 0 (local c 0,1): 24 entries / 4 waves = 6 ----
    #pragma unroll
    for (int j = 0; j < 6; ++j) {
        const int e = wav * 6 + j, cj = e / 12, ee = e % 12;
        gl2lds16(wb1B + (size_t)cj * 12288 + ee * 1024 + lane * 16,
                 wbuf + cj * 12288 + ee * 1024);
    }

    // ---- stage mask (its 20 c) + x tile ----
    for (int idx = tid; idx < BT * 20; idx += 256) {
        const int b = idx / 20, cc = idx % 20;
        msx[idx] = mask[((size_t)(b0 + b) * NI + i) * NC + c0 + cc] > 0.5f ? 1 : 0;
    }
    for (int idx = tid; idx < BT * (XPAD / 4); idx += 256) {
        const int row = idx / (XPAD / 4), fq = idx % (XPAD / 4);
        float4 v = make_float4(0.f, 0.f, 0.f, 0.f);
        if (fq < NF / 4)
            v = *(const float4*)(x + ((size_t)(b0 + row) * NI + i) * NF + fq * 4);
        *(float4*)&xs[row * XPAD + fq * 4] = v;
    }
    __syncthreads();   // xs/msx ready; drains prefetch(0)

    // ---- A-frags for mt = wav only (16 VGPRs) ----
    bf16x8 A[4];
    {
        const float* xr = xs + (wav * 16 + col) * XPAD;
        #pragma unroll
        for (int k = 0; k < 4; ++k) {
            if (k < 3 || quad == 0)
                A[k] = pack8(*(const float4*)(xr + k * 32 + quad * 8),
                             *(const float4*)(xr + k * 32 + quad * 8 + 4));
            else
                A[k] = __builtin_bit_cast(bf16x8, (u32x4){0, 0, 0, 0});
        }
    }

    // ---- 10 super-iters x 2 c ----
    f32x4 Hc[3];
    #pragma unroll
    for (int nt = 0; nt < 3; ++nt) Hc[nt] = (f32x4){0.f, 0.f, 0.f, 0.f};
    #pragma unroll 1
    for (int s = 0; s < 10; ++s) {
        if (s < 9) {
            #pragma unroll
            for (int j = 0; j < 6; ++j) {
                const int e = wav * 6 + j, cj = e / 12, ee = e % 12;
                gl2lds16(wb1B + (size_t)(2 * (s + 1) + cj) * 12288 + ee * 1024 + lane * 16,
                         wbuf + ((s + 1) & 1) * 24576 + cj * 12288 + ee * 1024);
            }
        }
        const unsigned char* bs = wbuf + (s & 1) * 24576;
        #pragma unroll
        for (int cj = 0; cj < 2; ++cj) {
            const int cc = 2 * s + cj;
            const unsigned char* bb = bs + cj * 12288;
            #pragma unroll
            for (int nt = 0; nt < 3; ++nt) {
                f32x4 P = (f32x4){0.f, 0.f, 0.f, 0.f};
                #pragma unroll
                for (int k = 0; k < 4; ++k)
                    P = __builtin_amdgcn_mfma_f32_16x16x32_bf16(
                        A[k],
                        *(const bf16x8*)(bb + (nt * 4 + k) * 1024 + (size_t)lane * 16),
                        P, 0, 0, 0);
                #pragma unroll
                for (int r = 0; r < 4; ++r)
                    Hc[nt][r] += (float)msx[(wav * 16 + quad * 4 + r) * 20 + cc] * P[r];
            }
        }
        __syncthreads();
    }

    // ---- store fp32 h-partials: hpart[((ch*32+bt)*8+i)][row][h] ----
    float* hp = hpart + ((size_t)(ch * 32 + bt) * 8 + i) * (BT * NH);
    #pragma unroll
    for (int nt = 0; nt < 3; ++nt) {
        const int h = nt * 16 + col;
        if (h < NH) {
            #pragma unroll
            for (int r = 0; r < 4; ++r)
                hp[(wav * 16 + quad * 4 + r) * NH + h] = Hc[nt][r];
        }
    }
}

// ---------------------------------------------------------------------------
// P2: pass2, f-split. grid 512 = 32 bt x 8 i x 2 fh; 256 threads (4 waves).
// Block streams its nt-range (fh0: nt 0-3, fh1: nt 4-6) of Wb2 over all 40 c.
// Sums the two fp32 h-partials -> bf16 hs -> A-frags; wave w owns mt=w.
// ---------------------------------------------------------------------------
__global__ __launch_bounds__(256, 2) void pass2_kernel(
    const float* __restrict__ mask, const float* __restrict__ b_final,
    const unsigned short* __restrict__ Wb2, const float* __restrict__ hpart,
    float* __restrict__ out)
{
    __shared__ __align__(16) unsigned char wbuf[2 * 32768];  // 2 x (4c x 8KB)
    __shared__ __align__(16) unsigned short hs[64 * 72];     // 9216 B
    __shared__ unsigned char msx[BT * NC];                   // 2560 B

    const int tid  = threadIdx.x;
    const int lane = tid & 63;
    const int wav  = tid >> 6;       // 0..3 == owned mt
    const int col  = lane & 15;
    const int quad = lane >> 4;
    const int i    = blockIdx.x & 7;
    const int fh   = (blockIdx.x >> 3) & 1;
    const int bt   = blockIdx.x >> 4;
    const int b0   = bt * BT;

    const unsigned char* wb2B = (const unsigned char*)Wb2 + (size_t)i * NC * 14336;
    const int epc  = fh ? 6 : 8;     // entries per c in this half
    const int ebase = fh ? 8 : 0;    // first entry index (nt*2+kk) of this half
    const int tot  = 4 * epc;        // entries per super-iter (4 c)

    // ---- prefetch super-iter 0 (c=0..3) ----
    #pragma unroll
    for (int j = 0; j < 8; ++j) {
        const int idx = wav + 4 * j;
        if (idx < tot) {
            const int cj = idx / epc, ee = idx % epc;
            gl2lds16(wb2B + (size_t)cj * 14336 + (ebase + ee) * 1024 + lane * 16,
                     wbuf + cj * 8192 + ee * 1024);
        }
    }

    // ---- stage mask (all 40 c) ----
    for (int idx = tid; idx < BT * NC; idx += 256) {
        const int b = idx / NC, c = idx % NC;
        msx[idx] = mask[((size_t)(b0 + b) * NI + i) * NC + c] > 0.5f ? 1 : 0;
    }
    // ---- zero hs, then fill with fp32-summed h (single bf16 rounding) ----
    for (int idx = tid; idx < 64 * 72 / 2; idx += 256) ((unsigned int*)hs)[idx] = 0;
    __syncthreads();
    {
        const float* h0 = hpart + ((size_t)(0 * 32 + bt) * 8 + i) * (BT * NH);
        const float* h1 = hpart + ((size_t)(1 * 32 + bt) * 8 + i) * (BT * NH);
        for (int idx = tid; idx < BT * NH; idx += 256) {
            const int row = idx / NH, h = idx % NH;
            hs[row * 72 + h] = f2bf(h0[idx] + h1[idx]);
        }
    }
    __syncthreads();   // hs ready; drains prefetch(0)

    // ---- A-frags for mt = wav (8 VGPRs); K=40 padded 64 (cols 40..63 = 0) ----
    bf16x8 A2[2];
    #pragma unroll
    for (int kk = 0; kk < 2; ++kk)
        A2[kk] = *(const bf16x8*)&hs[(wav * 16 + col) * 72 + kk * 32 + quad * 8];

    // ---- 10 super-iters x 4 c ----
    f32x4 Ot[4];
    #pragma unroll
    for (int j = 0; j < 4; ++j) Ot[j] = (f32x4){0.f, 0.f, 0.f, 0.f};
    #pragma unroll 1
    for (int s = 0; s < 10; ++s) {
        if (s < 9) {
            #pragma unroll
            for (int j = 0; j < 8; ++j) {
                const int idx = wav + 4 * j;
                if (idx < tot) {
                    const int cj = idx / epc, ee = idx % epc;
                    gl2lds16(wb2B + (size_t)(4 * (s + 1) + cj) * 14336
                                 + (ebase + ee) * 1024 + lane * 16,
                             wbuf + ((s + 1) & 1) * 32768 + cj * 8192 + ee * 1024);
                }
            }
        }
        const unsigned char* bs = wbuf + (s & 1) * 32768;
        #pragma unroll
        for (int cj = 0; cj < 4; ++cj) {
            const int c = 4 * s + cj;
            const unsigned char* bb = bs + cj * 8192;
            #pragma unroll
            for (int j = 0; j < 4; ++j) {
                if (fh == 0 || j < 3) {   // fh1 has 3 nt tiles
                    f32x4 P = (f32x4){0.f, 0.f, 0.f, 0.f};
                    P = __builtin_amdgcn_mfma_f32_16x16x32_bf16(
                        A2[0],
                        *(const bf16x8*)(bb + (j * 2 + 0) * 1024 + (size_t)lane * 16),
                        P, 0, 0, 0);
                    P = __builtin_amdgcn_mfma_f32_16x16x32_bf16(
                        A2[1],
                        *(const bf16x8*)(bb + (j * 2 + 1) * 1024 + (size_t)lane * 16),
                        P, 0, 0, 0);
                    #pragma unroll
                    for (int r = 0; r < 4; ++r)
                        Ot[j][r] += (float)msx[(wav * 16 + quad * 4 + r) * NC + c] * P[r];
                }
            }
        }
        __syncthreads();
    }

    // ---- epilogue: bias + relu, store ----
    #pragma unroll
    for (int j = 0; j < 4; ++j) {
        if (fh == 0 || j < 3) {
            const int f = (fh * 4 + j) * 16 + col;
            if (f < NF) {
                const float bias = b_final[i * NF + f];
                #pragma unroll
                for (int r = 0; r < 4; ++r) {
                    const int b = b0 + wav * 16 + quad * 4 + r;
                    out[((size_t)b * NI + i) * NF + f] = fmaxf(Ot[j][r] + bias, 0.f);
                }
            }
        }
    }
}

extern "C" void kernel_launch(void* const* d_in, const int* in_sizes, int n_in,
                              void* d_out, int out_size, void* d_ws, size_t ws_size,
                              hipStream_t stream) {
    const float* x       = (const float*)d_in[0];  // (2048, 8, 100)
    const float* tk_mask = (const float*)d_in[1];  // (2048, 8, 40)
    const float* A       = (const float*)d_in[2];  // (8, 40, 100, 41)
    const float* Bp      = (const float*)d_in[3];  // (8, 40, 41, 40)
    const float* b_final = (const float*)d_in[4];  // (8, 100)
    float* out = (float*)d_out;                    // (2048, 8, 100)

    // ws: Wb1 (3.93 MB) | Wb2 (4.59 MB) | hpart (2 x 32 x 8 x 64 x 40 fp32 = 5.24 MB)
    unsigned short* Wb1 = (unsigned short*)d_ws;
    unsigned short* Wb2 = Wb1 + (size_t)NI * NC * 768 * 8;
    float* hpart = (float*)(Wb2 + (size_t)NI * NC * 896 * 8);

    build_w_kernel<<<NI * NC, 512, 0, stream>>>(A, Bp, Wb1, Wb2);
    pass1_kernel<<<512, 256, 0, stream>>>(x, tk_mask, Wb1, hpart);
    pass2_kernel<<<512, 256, 0, stream>>>(tk_mask, b_final, Wb2, hpart, out);
}